// Round 3
// baseline (91.776 us; speedup 1.0000x reference)
//
#include <hip/hip_runtime.h>
#include <hip/hip_bf16.h>
#include <hip/hip_cooperative_groups.h>

namespace cg = cooperative_groups;

// SingleDimHistLayer: soft histogram via fine-grid deposit + 145-tap convolution.
//
// Math: out[b,k] = (1/N) * sum_n [ g(u_n - k) - g(u_n - k - 1) ],  g(v)=sigmoid(2.5 v),
//       u = x*256.  Terms negligible outside |u - k - 0.5| <= 4.5 -> 145 fine taps
//       at 1/16 resolution.
// Deposit: nearest fine node (midpoint rule), 1 INTEGER LDS atomic per sample.
//
// Round 3: launch-structure round. Measurement decomposes as
//   dur 59.8 = 41.4 (untouchable 256MiB harness ws-poison fill) + 18.4 (ours).
// Deposit/conv code byte-identical to round 2; the only change is collapsing
// {hist, reduce} into ONE cooperative launch (256 blocks co-resident, grid sync,
// 8 blocks reduce partials from ws). Clean A/B on launch/serialization overhead.

constexpr int KBINS   = 256;
constexpr int FSUB    = 16;                  // fine nodes per bin
constexpr int LPAD    = 64;                  // left halo (k=0 window reaches f=-64)
constexpr int TAPS    = 145;                 // window f in [16k-64, 16k+80]
// bank-skew addressing: addr = p + (p>>5); max logical p = 4224 -> 4356
constexpr int LDS_FH  = 4360;
constexpr int NPB     = 512 * 512;           // samples per batch
constexpr int BLK_PER_BATCH = 32;            // 8192 samples per block, grid = 256
constexpr int CHUNK   = NPB / BLK_PER_BATCH; // 8192
constexpr int THREADS = 1024;                // 16 waves/CU; 256 blocks on 256 CUs

__device__ __forceinline__ int skew(int p) { return p + (p >> 5); }

__global__ __launch_bounds__(THREADS)
void hist_kernel(const float* __restrict__ x, float* __restrict__ ws,
                 float* __restrict__ out) {
    __shared__ unsigned fh[LDS_FH];
    __shared__ float w[TAPS];
    const int tid = threadIdx.x;

    // zero fine hist
    for (int i = tid; i < LDS_FH; i += THREADS) fh[i] = 0u;

    // conv weights: w[j] = sigmoid(0.15625*(j-64)) - sigmoid(0.15625*(j-80))
    if (tid < TAPS) {
        float a = 0.15625f * (float)(tid - 64);
        float b = 0.15625f * (float)(tid - 80);
        w[tid] = 1.f / (1.f + __expf(-a)) - 1.f / (1.f + __expf(-b));
    }
    __syncthreads();

    const int b     = blockIdx.x / BLK_PER_BATCH;
    const int chunk = blockIdx.x % BLK_PER_BATCH;
    const float4* xv = (const float4*)(x + (size_t)b * NPB + (size_t)chunk * CHUNK);

    // deposit: 8192 samples/block, 2 float4 per thread, 1 int LDS atomic per sample.
    // addr = skew((int)(x*4096 + 64.5)) : LPAD and round-to-nearest folded into fmaf.
    #pragma unroll
    for (int it = 0; it < CHUNK / (4 * THREADS); ++it) {
        float4 v = xv[it * THREADS + tid];
        float vals[4] = {v.x, v.y, v.z, v.w};
        int addr[4];
        #pragma unroll
        for (int c = 0; c < 4; ++c) {
            float s = fmaf(vals[c], (float)(KBINS * FSUB), (float)LPAD + 0.5f);
            s = fminf(fmaxf(s, 0.f), 4224.f);            // defensive clamp (NaN -> 0)
            addr[c] = skew((int)s);
        }
        #pragma unroll
        for (int c = 0; c < 4; ++c)
            atomicAdd(&fh[addr[c]], 1u);
    }
    __syncthreads();

    // convolve: 4 threads per coarse bin, ~36 taps each, shfl pair-reduce.
    // bin k reads padded fine nodes [16k, 16k+144].
    {
        const int bin = tid >> 2;          // 0..255
        const int q   = tid & 3;
        const int j0  = q * 37;
        const int j1  = (j0 + 37 < TAPS) ? j0 + 37 : TAPS;
        const int base = bin * FSUB;
        float acc = 0.f;
        #pragma unroll 4
        for (int j = j0; j < j1; ++j)
            acc += w[j] * (float)fh[skew(base + j)];
        acc += __shfl_xor(acc, 1);
        acc += __shfl_xor(acc, 2);
        // non-atomic partial write: each (block, bin) slot written exactly once
        if (q == 0)
            ws[(size_t)blockIdx.x * KBINS + bin] = acc;
    }

    // grid-wide sync, then 8 blocks reduce 32 partials/batch -> out
    cg::this_grid().sync();

    if (blockIdx.x < 8) {
        const int batch = blockIdx.x;
        const int bin = tid >> 2;          // 0..255
        const int q   = tid & 3;           // sums partial chunks q*8 .. q*8+7
        const float* p = ws + (size_t)batch * BLK_PER_BATCH * KBINS + bin;
        float s = 0.f;
        #pragma unroll
        for (int i = 0; i < 8; ++i)
            s += p[(size_t)(q * 8 + i) * KBINS];
        s += __shfl_xor(s, 1);
        s += __shfl_xor(s, 2);
        if (q == 0)
            out[batch * KBINS + bin] = s * (1.f / (float)NPB);
    }
}

extern "C" void kernel_launch(void* const* d_in, const int* in_sizes, int n_in,
                              void* d_out, int out_size, void* d_ws, size_t ws_size,
                              hipStream_t stream) {
    const float* x = (const float*)d_in[0];
    float* out = (float*)d_out;
    float* ws  = (float*)d_ws;     // needs 256*256*4 = 256 KB; ws is far larger
    const int B = in_sizes[0] / NPB;   // 8

    void* args[] = {(void*)&x, (void*)&ws, (void*)&out};
    hipLaunchCooperativeKernel((const void*)hist_kernel,
                               dim3(B * BLK_PER_BATCH), dim3(THREADS),
                               args, 0, stream);
}